// Round 4
// baseline (114.974 us; speedup 1.0000x reference)
//
#include <hip/hip_runtime.h>

#define NUM_HEADS 16
#define HEAD_DIM  128
#define SEQ       2048
#define KT_STRIDE 8192   // bf16 elems per k-tile group in KF/VF (16 chunks * 512)

typedef __attribute__((ext_vector_type(8))) unsigned short us8;
typedef __attribute__((ext_vector_type(8))) __bf16 bf16x8;
typedef __attribute__((ext_vector_type(4))) float f32x4;
typedef __attribute__((ext_vector_type(16))) float f32x16;
typedef __attribute__((ext_vector_type(4))) unsigned u32x4;
typedef __attribute__((ext_vector_type(2))) unsigned u32x2;

static __device__ inline unsigned short f2bf(float x) {   // RNE
    union { float f; unsigned u; } v; v.f = x;
    unsigned r = v.u + 0x7FFFu + ((v.u >> 16) & 1u);
    return (unsigned short)(r >> 16);
}
static __device__ inline unsigned pk2bf(float a, float b) {
    return (unsigned)f2bf(a) | ((unsigned)f2bf(b) << 16);
}
static __device__ inline float fast_exp2(float x) {
#if __has_builtin(__builtin_amdgcn_exp2f)
    return __builtin_amdgcn_exp2f(x);
#else
    return exp2f(x);
#endif
}
// pack hi16(clo) into lo half, hi16(chi) into hi half (both truncated bf16)
static __device__ inline unsigned pack_hi(unsigned clo, unsigned chi) {
#if __has_builtin(__builtin_amdgcn_perm)
    return __builtin_amdgcn_perm(chi, clo, 0x07060302u);
#else
    return (clo >> 16) | (chi & 0xffff0000u);
#endif
}
static __device__ inline f32x16 mfma32(us8 a, us8 b, f32x16 c) {
    return __builtin_amdgcn_mfma_f32_32x32x16_bf16(
        __builtin_bit_cast(bf16x8, a), __builtin_bit_cast(bf16x8, b), c, 0, 0, 0);
}

// ---------- pre-pass: write K and V^T in exact 32x32x16 A-fragment order ----------
// 512 blocks (2 which x 2 kh x 32 kt x 4 kvh), 32 rows each -> 2 blocks/CU
__global__ __launch_bounds__(256)
void prep_frag(const float* __restrict__ K, const float* __restrict__ V,
               unsigned short* __restrict__ KF, unsigned short* __restrict__ VF)
{
    const int bx  = (int)blockIdx.x, t = (int)threadIdx.x;
    const int which = bx & 1, khb = (bx >> 1) & 1, kt = (bx >> 2) & 31, kvh = bx >> 7;
    __shared__ __align__(16) float Ls[32][132];

    const float* src = (which ? V : K) + ((size_t)kvh * SEQ + kt * 64 + khb * 32) * HEAD_DIM;
    #pragma unroll
    for (int i = 0; i < 4; ++i) {
        const int idx = t + i * 256;
        const int r = idx >> 5, c4 = idx & 31;
        // nt: K/V inputs are read exactly once — don't pollute L2
        f32x4 v = __builtin_nontemporal_load((const f32x4*)(src + (size_t)r * HEAD_DIM + c4 * 4));
        *(f32x4*)&Ls[r][c4 * 4] = v;
    }
    __syncthreads();

    if (!which) {  // K fragments
        #pragma unroll
        for (int i = 0; i < 2; ++i) {
            const int c = t + i * 256;              // 0..511
            const int lane = c & 63, ds = (c >> 6) & 3, mat = (c >> 8) & 1;
            const int H = lane >> 5;
            const int row = lane & 31;              // local row within our 32
            const int dim = mat * 64 + ds * 16 + H * 8;
            u32x4 pk;
            #pragma unroll
            for (int jj = 0; jj < 4; ++jj)
                pk[jj] = pk2bf(Ls[row][dim + 2*jj], Ls[row][dim + 2*jj + 1]);
            *(us8*)(KF + ((size_t)(kvh * 32 + kt) * 16 + khb * 8 + mat * 4 + ds) * 512 + lane * 8)
                = __builtin_bit_cast(us8, pk);
        }
    } else {       // V^T fragments
        #pragma unroll
        for (int i = 0; i < 2; ++i) {
            const int c = t + i * 256;
            const int lane = c & 63, db = (c >> 6) & 3, ks = (c >> 8) & 1;
            const int H = lane >> 5;
            const int s0 = ks * 16 + H * 8;         // local row within our 32
            const int d  = db * 32 + (lane & 31);
            u32x4 pk;
            #pragma unroll
            for (int jj = 0; jj < 4; ++jj)
                pk[jj] = pk2bf(Ls[s0 + 2*jj][d], Ls[s0 + 2*jj + 1][d]);
            *(us8*)(VF + ((size_t)(kvh * 32 + kt) * 16 + khb * 8 + ks * 4 + db) * 512 + lane * 8)
                = __builtin_bit_cast(us8, pk);
        }
    }
}

// ---------- main: XCD-affinity swizzle so each XCD's K/V working set is 1 MB ----------
// HW round-robins blockIdx to XCDs (xcd = bx & 7). XCD pair {2k,2k+1} handles only
// kv-head-group k: KF/VF slice (1 MB) stays L2-resident instead of thrashing through
// the shared L3 (~17 TB/s demand measured in R3 — the wall). nt on Q/Out streams
// protects that residency. Body identical to R3 (register-dieted, 3 waves/SIMD).
__global__ __launch_bounds__(256, 3)
void diff_attn_mfma13(const float* __restrict__ Q,
                      const unsigned short* __restrict__ KF,
                      const unsigned short* __restrict__ VF,
                      float* __restrict__ Out)
{
    __shared__ float cb[2][32][136];   // epilogue-only combine buffer
    __shared__ float rsb[2][2][32];

    const int t   = (int)threadIdx.x;
    const int wv  = t >> 6;
    const int ln  = t & 63;
    const int mat = wv >> 1;        // 0: softmax1 (dims 0..63), 1: softmax2 (64..127)
    const int kh  = wv & 1;         // k-half of the 64-k tile
    const int q   = ln & 31;        // q-col
    const int H   = ln >> 5;

    // grid 1024; (xcd, slot) -> (kvh fixed per XCD pair, h, qt) — heavy qt first
    const int bx   = (int)blockIdx.x;
    const int xcd  = bx & 7;
    const int slot = bx >> 3;                    // 0..127 per XCD
    const int kvh  = xcd >> 1;                   // 2 XCDs per kv-head group
    const int h    = kvh * 4 + (slot & 3);       // h>>2 == kvh
    const int qt   = 63 - (2 * (slot >> 2) + (xcd & 1));   // 63..0 descending
    const int nkt  = (qt >> 1) + 1;              // 32..1

    const unsigned short* kfb = KF + ((size_t)kvh * 32 * 16 + kh * 8 + mat * 4) * 512 + ln * 8;
    const unsigned short* vfb = VF + ((size_t)kvh * 32 * 16 + kh * 8) * 512 + ln * 8;

    const float qscale = 0.125f * 1.44269504088896340736f;  // 1/8 * log2(e)
    const int q0c = qt * 32;

    us8 qhi[4];
    {
        const float* qr = Q + ((size_t)h * SEQ + q0c + q) * HEAD_DIM + mat * 64;
        #pragma unroll
        for (int ds = 0; ds < 4; ++ds) {
            const int d0 = ds * 16 + H * 8;
            // nt: Q rows are read exactly once
            f32x4 x0 = __builtin_nontemporal_load((const f32x4*)(qr + d0));
            f32x4 x1 = __builtin_nontemporal_load((const f32x4*)(qr + d0 + 4));
            us8 hi8;
            #pragma unroll
            for (int j = 0; j < 4; ++j) hi8[j] = f2bf(x0[j] * qscale);
            #pragma unroll
            for (int j = 0; j < 4; ++j) hi8[4 + j] = f2bf(x1[j] * qscale);
            qhi[ds] = hi8;
        }
    }

    f32x16 o[4];                   // O^T: dim = db*32+(r&3)+8*(r>>2)+4H, q-col = q
    #pragma unroll
    for (int i = 0; i < 4; ++i) o[i] = (f32x16)0.f;
    f32x4 rsv = (f32x4)0.f;        // row-sum partials

    // ---- main loop ----
    us8 ka[4];
    f32x16 s;

    // prologue: scores for tile 0
    #pragma unroll
    for (int ds = 0; ds < 4; ++ds) ka[ds] = *(const us8*)(kfb + ds * 512);
    s = (f32x16)0.f;
    #pragma unroll
    for (int ds = 0; ds < 4; ++ds) s = mfma32(ka[ds], qhi[ds], s);

    // body: consumes s=S(j); loads ka<-K(j+1) at start; rewrites s=S(j+1) at end.
    auto body = [&](int j, bool last) {
        const unsigned short* vb = vfb + (size_t)j * KT_STRIDE;
        us8 va0[4];
        #pragma unroll
        for (int c4 = 0; c4 < 4; ++c4) va0[c4] = *(const us8*)(vb + c4 * 512);
        if (!last) {
            const unsigned short* kb = kfb + (size_t)(j + 1) * KT_STRIDE;
            #pragma unroll
            for (int ds = 0; ds < 4; ++ds) ka[ds] = *(const us8*)(kb + ds * 512);
        }

        // ---- ks = 0: exp2 rows 0..7 ----
        unsigned c0[8];
        if (last) {
            const int kg0 = j * 64 + kh * 32 + 4 * H;
            const int qg  = q0c + q;
            #pragma unroll
            for (int r = 0; r < 8; ++r) {
                const int kg = kg0 + (r & 3) + ((r >> 2) << 3);
                float e = (kg <= qg) ? fast_exp2(s[r]) : 0.f;
                c0[r] = __builtin_bit_cast(unsigned, e);
            }
        } else {
            #pragma unroll
            for (int r = 0; r < 8; ++r)
                c0[r] = __builtin_bit_cast(unsigned, fast_exp2(s[r]));
        }
        unsigned pA = pack_hi(c0[0], c0[1]);
        unsigned pB = pack_hi(c0[2], c0[3]);
        unsigned pC = pack_hi(c0[4], c0[5]);
        unsigned pD = pack_hi(c0[6], c0[7]);
        rsv[0] += __builtin_bit_cast(float, pA << 16);
        rsv[1] += __builtin_bit_cast(float, pA & 0xffff0000u);
        rsv[2] += __builtin_bit_cast(float, pB << 16);
        rsv[3] += __builtin_bit_cast(float, pB & 0xffff0000u);
        rsv[0] += __builtin_bit_cast(float, pC << 16);
        rsv[1] += __builtin_bit_cast(float, pC & 0xffff0000u);
        rsv[2] += __builtin_bit_cast(float, pD << 16);
        rsv[3] += __builtin_bit_cast(float, pD & 0xffff0000u);
        u32x4 bw;
#if __has_builtin(__builtin_amdgcn_permlane32_swap)
        {
            u32x2 r02 = __builtin_amdgcn_permlane32_swap(pA, pC, false, false);
            u32x2 r13 = __builtin_amdgcn_permlane32_swap(pB, pD, false, false);
            bw[0] = r02[0]; bw[1] = r13[0]; bw[2] = r02[1]; bw[3] = r13[1];
        }
#else
        {
            const unsigned x1 = H ? pA : pC;
            const unsigned x2 = H ? pB : pD;
            const unsigned t1 = (unsigned)__shfl_xor((int)x1, 32, 64);
            const unsigned t2 = (unsigned)__shfl_xor((int)x2, 32, 64);
            bw[0] = H ? t1 : pA;
            bw[1] = H ? t2 : pB;
            bw[2] = H ? pC : t1;
            bw[3] = H ? pD : t2;
        }
#endif
        us8 bp = __builtin_bit_cast(us8, bw);

        // issue second V half now: covered by ks0 PV MFMAs + ks1 exp2/pack
        us8 va1[4];
        #pragma unroll
        for (int c4 = 0; c4 < 4; ++c4) va1[c4] = *(const us8*)(vb + (4 + c4) * 512);

        #pragma unroll
        for (int db = 0; db < 4; ++db) o[db] = mfma32(va0[db], bp, o[db]);

        // ---- ks = 1: exp2 rows 8..15 ----
        if (last) {
            const int kg0 = j * 64 + kh * 32 + 4 * H;
            const int qg  = q0c + q;
            #pragma unroll
            for (int r = 8; r < 16; ++r) {
                const int kg = kg0 + (r & 3) + ((r >> 2) << 3);
                float e = (kg <= qg) ? fast_exp2(s[r]) : 0.f;
                c0[r - 8] = __builtin_bit_cast(unsigned, e);
            }
        } else {
            #pragma unroll
            for (int r = 8; r < 16; ++r)
                c0[r - 8] = __builtin_bit_cast(unsigned, fast_exp2(s[r]));
        }
        pA = pack_hi(c0[0], c0[1]);
        pB = pack_hi(c0[2], c0[3]);
        pC = pack_hi(c0[4], c0[5]);
        pD = pack_hi(c0[6], c0[7]);
        rsv[0] += __builtin_bit_cast(float, pA << 16);
        rsv[1] += __builtin_bit_cast(float, pA & 0xffff0000u);
        rsv[2] += __builtin_bit_cast(float, pB << 16);
        rsv[3] += __builtin_bit_cast(float, pB & 0xffff0000u);
        rsv[0] += __builtin_bit_cast(float, pC << 16);
        rsv[1] += __builtin_bit_cast(float, pC & 0xffff0000u);
        rsv[2] += __builtin_bit_cast(float, pD << 16);
        rsv[3] += __builtin_bit_cast(float, pD & 0xffff0000u);
#if __has_builtin(__builtin_amdgcn_permlane32_swap)
        {
            u32x2 r02 = __builtin_amdgcn_permlane32_swap(pA, pC, false, false);
            u32x2 r13 = __builtin_amdgcn_permlane32_swap(pB, pD, false, false);
            bw[0] = r02[0]; bw[1] = r13[0]; bw[2] = r02[1]; bw[3] = r13[1];
        }
#else
        {
            const unsigned x1 = H ? pA : pC;
            const unsigned x2 = H ? pB : pD;
            const unsigned t1 = (unsigned)__shfl_xor((int)x1, 32, 64);
            const unsigned t2 = (unsigned)__shfl_xor((int)x2, 32, 64);
            bw[0] = H ? t1 : pA;
            bw[1] = H ? t2 : pB;
            bw[2] = H ? pC : t1;
            bw[3] = H ? pD : t2;
        }
#endif
        bp = __builtin_bit_cast(us8, bw);
        #pragma unroll
        for (int db = 0; db < 4; ++db) o[db] = mfma32(va1[db], bp, o[db]);

        // scores for next tile (ka loads have had the whole body to land)
        if (!last) {
            s = (f32x16)0.f;
            #pragma unroll
            for (int ds = 0; ds < 4; ++ds) s = mfma32(ka[ds], qhi[ds], s);
        }
    };

    for (int j = 0; j < nkt - 1; ++j) body(j, false);
    body(nkt - 1, true);

    // ---- epilogue ----
    __syncthreads();
    {
        float rsc = (rsv[0] + rsv[1]) + (rsv[2] + rsv[3]);
        rsc += __shfl_xor(rsc, 32, 64);
        if (ln < 32) rsb[mat][kh][ln] = rsc;
    }
    if (kh == 1) {
        #pragma unroll
        for (int db = 0; db < 4; ++db)
            #pragma unroll
            for (int i = 0; i < 4; ++i) {
                float4 v = { o[db][i*4+0], o[db][i*4+1], o[db][i*4+2], o[db][i*4+3] };
                *(float4*)&cb[mat][q][db * 32 + 8 * i + 4 * H] = v;
            }
    }
    __syncthreads();
    if (kh == 0) {
        const float l = rsb[mat][0][q] + rsb[mat][1][q];
        const float a = mat ? (0.16f / l) : (0.2f / l);
        #pragma unroll
        for (int db = 0; db < 4; ++db)
            #pragma unroll
            for (int i = 0; i < 4; ++i) {
                float4 v = *(float4*)&cb[mat][q][db * 32 + 8 * i + 4 * H];
                o[db][i*4+0] = (o[db][i*4+0] + v.x) * a;
                o[db][i*4+1] = (o[db][i*4+1] + v.y) * a;
                o[db][i*4+2] = (o[db][i*4+2] + v.z) * a;
                o[db][i*4+3] = (o[db][i*4+3] + v.w) * a;
            }
        if (mat == 1) {
            #pragma unroll
            for (int db = 0; db < 4; ++db)
                #pragma unroll
                for (int i = 0; i < 4; ++i) {
                    float4 v = { o[db][i*4+0], o[db][i*4+1], o[db][i*4+2], o[db][i*4+3] };
                    *(float4*)&cb[1][q][db * 32 + 8 * i + 4 * H] = v;
                }
        }
    }
    __syncthreads();
    if (wv == 0) {
        float* ob = Out + ((size_t)h * SEQ + q0c + q) * HEAD_DIM;
        #pragma unroll
        for (int db = 0; db < 4; ++db)
            #pragma unroll
            for (int i = 0; i < 4; ++i) {
                float4 v = *(float4*)&cb[1][q][db * 32 + 8 * i + 4 * H];
                f32x4 r;
                r[0] = o[db][i*4+0] - v.x;
                r[1] = o[db][i*4+1] - v.y;
                r[2] = o[db][i*4+2] - v.z;
                r[3] = o[db][i*4+3] - v.w;
                // nt: Out is written once, never re-read
                __builtin_nontemporal_store(r, (f32x4*)(ob + db * 32 + 8 * i + 4 * H));
            }
    }
}

extern "C" void kernel_launch(void* const* d_in, const int* in_sizes, int n_in,
                              void* d_out, int out_size, void* d_ws, size_t ws_size,
                              hipStream_t stream) {
    const float* Q = (const float*)d_in[0];
    const float* K = (const float*)d_in[1];
    const float* V = (const float*)d_in[2];
    float* Out = (float*)d_out;

    unsigned short* KF = (unsigned short*)d_ws;             // 2 MB
    unsigned short* VF = KF + (size_t)4 * SEQ * HEAD_DIM;   // 2 MB

    prep_frag<<<512, 256, 0, stream>>>(K, V, KF, VF);
    diff_attn_mfma13<<<1024, 256, 0, stream>>>(Q, KF, VF, Out);
}